// Round 4
// baseline (73.468 us; speedup 1.0000x reference)
//
#include <hip/hip_runtime.h>

// PatchQuantumGenerator, round 4.
// Algorithm (verified r2/r3): fold circuit into M_g[16x32] complex (f16),
// amps = M_g * v(b), v rank-1 real from sincos of x; f16 MFMA GEMM.
// r4 changes:
//  - precompute: 8 single-wave blocks (g x column-half). Columns are
//    independent under amp-index gates => no inter-wave traffic, and
//    single-wave __syncthreads is ~free (kills the 28 4-wave barriers).
//  - main: per-block LDS staging of sincos (160 instead of 2560 sincos)
//    and of the 32 f16 B-vectors; lanes fetch B-frags via ds_read_b128.

#define NGEN 4
#define NLAY 4
#define NQ   5

typedef _Float16 half8 __attribute__((ext_vector_type(8)));
typedef _Float16 half4 __attribute__((ext_vector_type(4)));
typedef float    f32x4 __attribute__((ext_vector_type(4)));

// ---------------------------------------------------------------------------
// Kernel A: block = (g, colhalf). 64 threads (1 wave). State S[amp][colL]
// (32 x 16 complex) in LDS, stride 17 floats. Emits A-fragment layout:
//   element (m,k): lane L=(k>>3)*16+m, reg j=k&7; plane p (0=re,1=im):
//   wsA[((g*2+p)*64+L)*8+j]
// ---------------------------------------------------------------------------
__global__ __launch_bounds__(64) void pqg_precompute(
    const float* __restrict__ w, _Float16* __restrict__ wsA)
{
    __shared__ float gm[NLAY * NQ * 8];
    __shared__ float Sr[32 * 17];
    __shared__ float Si[32 * 17];

    const int g  = blockIdx.x >> 1;
    const int ch = blockIdx.x & 1;        // column half: cols ch*16..ch*16+15
    const int t  = threadIdx.x;           // 0..63

    // Gate matrices (Rot = RZ(omega) RY(theta) RZ(phi); verified r1-r3).
    if (t < NLAY * NQ) {
        const float* wp = w + (g * (NLAY * NQ) + t) * 3;
        const float phi = wp[0], theta = wp[1], omega = wp[2];
        const float a = 0.5f * (phi + omega);
        const float bb = 0.5f * (phi - omega);
        const float h = 0.5f * theta;
        const float sa = __sinf(a), ca = __cosf(a);
        const float sb = __sinf(bb), cb = __cosf(bb);
        const float st = __sinf(h), ct = __cosf(h);
        float* m = &gm[t * 8];
        m[0] =  ca * ct;  m[1] = -sa * ct;
        m[2] = -cb * st;  m[3] = -sb * st;
        m[4] =  cb * st;  m[5] = -sb * st;
        m[6] =  ca * ct;  m[7] =  sa * ct;
    }

    // Init S = identity columns ch*16..ch*16+15.
#pragma unroll
    for (int r = 0; r < 8; ++r) {
        const int idx = r * 64 + t;       // 0..511
        const int amp = idx >> 4;
        const int cL  = idx & 15;
        Sr[amp * 17 + cL] = (amp == ch * 16 + cL) ? 1.0f : 0.0f;
        Si[amp * 17 + cL] = 0.0f;
    }
    __syncthreads();

    const int colL = t & 15;
    const int pg   = t >> 4;              // 0..3

    int gate = 0;
#pragma clang loop unroll(disable)
    for (int l = 0; l < NLAY; ++l) {
#pragma clang loop unroll(disable)
        for (int q = 0; q < NQ; ++q, ++gate) {
            const float* m = &gm[gate * 8];
            const float u00r = m[0], u00i = m[1], u01r = m[2], u01i = m[3];
            const float u10r = m[4], u10i = m[5], u11r = m[6], u11i = m[7];
            const int sb = 16 >> q;
            const int lowm = sb - 1;
#pragma unroll
            for (int r = 0; r < 4; ++r) {
                const int p = r * 4 + pg;                       // pair 0..15
                const int i = ((p & ~lowm) << 1) | (p & lowm);
                const int j = i | sb;
                const int ii = i * 17 + colL, jj = j * 17 + colL;
                const float ar = Sr[ii], ai = Si[ii];
                const float br = Sr[jj], bi = Si[jj];
                Sr[ii] = u00r * ar - u00i * ai + u01r * br - u01i * bi;
                Si[ii] = u00r * ai + u00i * ar + u01r * bi + u01i * br;
                Sr[jj] = u10r * ar - u10i * ai + u11r * br - u11i * bi;
                Si[jj] = u10r * ai + u10i * ar + u11r * bi + u11i * br;
            }
            __syncthreads();
        }

        // CNOT chain as one amp-index permutation (verified r3):
        // S_new[a] = S_old[c0(c1(c2(c3(c4(a)))))].
        const int rr = l + 1;
        float tr[8], ti[8];
#pragma unroll
        for (int r = 0; r < 8; ++r) {
            const int idx = r * 64 + t;
            const int amp = idx >> 4;
            const int cc  = idx & 15;
            int v = amp;
#pragma unroll
            for (int q = 4; q >= 0; --q) {
                const int cb2 = 16 >> q;
                int tq = q + rr; if (tq >= NQ) tq -= NQ;
                const int tb2 = 16 >> tq;
                if (v & cb2) v ^= tb2;
            }
            tr[r] = Sr[v * 17 + cc];
            ti[r] = Si[v * 17 + cc];
        }
        __syncthreads();
#pragma unroll
        for (int r = 0; r < 8; ++r) {
            const int idx = r * 64 + t;
            Sr[(idx >> 4) * 17 + (idx & 15)] = tr[r];
            Si[(idx >> 4) * 17 + (idx & 15)] = ti[r];
        }
        __syncthreads();
    }

    // Emit rows 0..15 of this column half, both planes: 512 f16, 8/thread.
#pragma unroll
    for (int r = 0; r < 8; ++r) {
        const int idx = r * 64 + t;       // 0..511
        const int plane = idx >> 8;
        const int e = idx & 255;
        const int row = e >> 4;           // 0..15
        const int cL  = e & 15;
        const int col = ch * 16 + cL;
        const int L = (col >> 3) * 16 + row;
        const int jj = col & 7;
        const float val = plane ? Si[row * 17 + cL] : Sr[row * 17 + cL];
        wsA[((g * 2 + plane) * 64 + L) * 8 + jj] = (_Float16)val;
    }
}

// ---------------------------------------------------------------------------
// Kernel B: block = 32 batches x 4 g (one wave per g). LDS staging:
//  phase1: 160 threads do the block's 160 sincos (coalesced x read).
//  phase2: 256 threads build v(b)[k] f16, layout vf[b][k] stride 40 f16
//          (80 B) -> 16B-aligned ds_read_b128, 2-way bank alias (free).
//  phase3: lane reads its B-frag half8, 2 MFMA, epilogue (verified r2/r3).
// ---------------------------------------------------------------------------
#define TPB 2   // 16-batch tiles per wave; block covers 32 batches

__global__ __launch_bounds__(256) void pqg_main(
    const float* __restrict__ x,
    const _Float16* __restrict__ wsA,
    float* __restrict__ out)
{
    __shared__ float scC[160];
    __shared__ float scS[160];
    __shared__ __align__(16) _Float16 vf[32 * 40];

    const int tid = threadIdx.x;
    const int lane = tid & 63;
    const int g = tid >> 6;
    const int quad = lane >> 4;
    const int n = lane & 15;
    const int b0 = blockIdx.x * 32;

    // A fragments (independent of phase1; loads issue before the barrier).
    const half8 Ar = *(const half8*)(wsA + ((g * 2 + 0) * 64 + lane) * 8);
    const half8 Ai = *(const half8*)(wsA + ((g * 2 + 1) * 64 + lane) * 8);

    // Phase 1: sincos staging. tid = bl*5+q -> x[b0*5 + tid] is coalesced.
    if (tid < 160) {
        const float tt = 0.5f * x[b0 * 5 + tid];
        scS[tid] = __sinf(tt);
        scC[tid] = __cosf(tt);
    }
    __syncthreads();

    // Phase 2: thread -> (bl = tid>>3, kq = tid&7); v[bl][kq*4 .. kq*4+3].
    // k bits: bit4=q0, bit3=q1, bit2=q2 (from kq), bit1=q3, bit0=q4.
    {
        const int bl = tid >> 3;
        const int kq = tid & 7;
        const float* C = &scC[bl * 5];
        const float* S = &scS[bl * 5];
        const float t0 = (kq & 4) ? S[0] : C[0];
        const float t1 = (kq & 2) ? S[1] : C[1];
        const float t2 = (kq & 1) ? S[2] : C[2];
        const float p = t0 * t1 * t2;
        const float pc3 = p * C[3], ps3 = p * S[3];
        half4 hv;
        hv[0] = (_Float16)(pc3 * C[4]);
        hv[1] = (_Float16)(pc3 * S[4]);
        hv[2] = (_Float16)(ps3 * C[4]);
        hv[3] = (_Float16)(ps3 * S[4]);
        *(half4*)(vf + bl * 40 + kq * 4) = hv;   // 8B-aligned ds_write_b64
    }
    __syncthreads();

    // Phase 3: MFMA tiles.
#pragma unroll
    for (int t = 0; t < TPB; ++t) {
        const int bl = t * 16 + n;
        const int b = b0 + bl;

        const half8 Bf = *(const half8*)(vf + bl * 40 + quad * 8);  // 16B read

        f32x4 accR = {0.f, 0.f, 0.f, 0.f};
        f32x4 accI = {0.f, 0.f, 0.f, 0.f};
        accR = __builtin_amdgcn_mfma_f32_16x16x32_f16(Ar, Bf, accR, 0, 0, 0);
        accI = __builtin_amdgcn_mfma_f32_16x16x32_f16(Ai, Bf, accI, 0, 0, 0);

        // C/D: col = lane&15 (batch), row = quad*4 + reg (output k).
        const float p0 = accR[0] * accR[0] + accI[0] * accI[0];
        const float p1 = accR[1] * accR[1] + accI[1] * accI[1];
        const float p2 = accR[2] * accR[2] + accI[2] * accI[2];
        const float p3 = accR[3] * accR[3] + accI[3] * accI[3];

        float mx = fmaxf(fmaxf(p0, p1), fmaxf(p2, p3));
        mx = fmaxf(mx, __shfl_xor(mx, 16));
        mx = fmaxf(mx, __shfl_xor(mx, 32));
        const float inv = 1.0f / mx;

        const float4 o = make_float4(p0 * inv, p1 * inv, p2 * inv, p3 * inv);
        *(float4*)(out + (size_t)b * 64 + g * 16 + quad * 4) = o;
    }
}

extern "C" void kernel_launch(void* const* d_in, const int* in_sizes, int n_in,
                              void* d_out, int out_size, void* d_ws, size_t ws_size,
                              hipStream_t stream) {
    const float* x = (const float*)d_in[0];   // [B, 5]
    const float* w = (const float*)d_in[1];   // [4, 4, 5, 3]
    float* out = (float*)d_out;               // [B, 64]
    _Float16* wsA = (_Float16*)d_ws;          // 8 KB of d_ws

    const int B = in_sizes[0] / NQ;           // 65536

    pqg_precompute<<<NGEN * 2, 64, 0, stream>>>(w, wsA);
    pqg_main<<<B / 32, 256, 0, stream>>>(x, wsA, out);
}

// Round 5
// 67.603 us; speedup vs baseline: 1.0867x; 1.0867x over previous
//
#include <hip/hip_runtime.h>

// PatchQuantumGenerator, round 5: single fused kernel.
// Per block (one g, 512 batches): build M_g = P * U (16x32 complex) by ROW
// propagation in LDS (gates right-multiplied in reverse circuit order),
// emit f16 MFMA A-fragments to LDS, then GEMM amps = M_g * v(b) with
// 16x16x32 f16 MFMA (B-frag bit-map verified in r2-r4).

#define NGEN 4
#define NLAY 4
#define NQ   5

typedef _Float16 half8 __attribute__((ext_vector_type(8)));
typedef float    f32x4 __attribute__((ext_vector_type(4)));

__global__ __launch_bounds__(256) void pqg_fused(
    const float* __restrict__ x,      // [B,5]
    const float* __restrict__ wts,    // [4,4,5,3]
    float* __restrict__ out)          // [B,64]
{
    __shared__ float gm[NLAY * NQ * 8];
    __shared__ float Mr[16 * 33];
    __shared__ float Mi[16 * 33];
    __shared__ __align__(16) _Float16 afr[512];
    __shared__ __align__(16) _Float16 afi[512];
    __shared__ float scC[512 * 5];
    __shared__ float scS[512 * 5];

    const int t  = threadIdx.x;
    const int g  = blockIdx.x & 3;
    const int b0 = (blockIdx.x >> 2) * 512;

    // ---- Phase S: stage sincos for this block's 512 batches (2560 values).
    // Coalesced float2 loads; independent of the M build (overlaps it).
    {
        const float2* xb = (const float2*)(x + (size_t)b0 * 5);
#pragma unroll
        for (int i = 0; i < 5; ++i) {
            const int e = i * 256 + t;           // 0..1279 float2s
            const float2 v = xb[e];
            scS[2 * e + 0] = __sinf(0.5f * v.x);
            scC[2 * e + 0] = __cosf(0.5f * v.x);
            scS[2 * e + 1] = __sinf(0.5f * v.y);
            scC[2 * e + 1] = __cosf(0.5f * v.y);
        }
    }

    // ---- Gate matrices (Rot = RZ(omega) RY(theta) RZ(phi); verified r1-r4).
    if (t < NLAY * NQ) {
        const float* wp = wts + (g * (NLAY * NQ) + t) * 3;
        const float phi = wp[0], theta = wp[1], omega = wp[2];
        const float a = 0.5f * (phi + omega);
        const float bb = 0.5f * (phi - omega);
        const float h = 0.5f * theta;
        const float sa = __sinf(a), ca = __cosf(a);
        const float sb = __sinf(bb), cb = __cosf(bb);
        const float st = __sinf(h), ct = __cosf(h);
        float* m = &gm[t * 8];
        m[0] =  ca * ct;  m[1] = -sa * ct;   // u00
        m[2] = -cb * st;  m[3] = -sb * st;   // u01
        m[4] =  cb * st;  m[5] = -sb * st;   // u10
        m[6] =  ca * ct;  m[7] =  sa * ct;   // u11
    }

    // ---- M init: M = P (rows 0..15 of identity), stride 33.
#pragma unroll
    for (int h = 0; h < 2; ++h) {
        const int idx = h * 256 + t;          // 0..511
        const int r = idx >> 5, c = idx & 31;
        Mr[r * 33 + c] = (r == c) ? 1.0f : 0.0f;
        Mi[r * 33 + c] = 0.0f;
    }
    __syncthreads();

    // ---- Build M = P*U, processing gates in REVERSE circuit order.
    const int row = t & 15;
    const int p   = t >> 4;                   // 0..15

#pragma clang loop unroll(disable)
    for (int l = NLAY - 1; l >= 0; --l) {
        // CNOT group of layer l (applied after the Rots => processed first).
        // Column gather: new[., i] = old[., sigma(i)], sigma = apply
        // q=0..4 ASCENDING: if (v & cb_q) v ^= tb_q  (transpose of the
        // verified forward perm, which used descending q).
        {
            const int c0 = p, c1 = p + 16;
            int v0 = c0, v1 = c1;
#pragma unroll
            for (int q = 0; q < NQ; ++q) {
                const int cb = 16 >> q;
                int tq = q + l + 1; if (tq >= NQ) tq -= NQ;
                const int tb = 16 >> tq;
                if (v0 & cb) v0 ^= tb;
                if (v1 & cb) v1 ^= tb;
            }
            const float a0r = Mr[row * 33 + v0], a0i = Mi[row * 33 + v0];
            const float a1r = Mr[row * 33 + v1], a1i = Mi[row * 33 + v1];
            __syncthreads();
            Mr[row * 33 + c0] = a0r;  Mi[row * 33 + c0] = a0i;
            Mr[row * 33 + c1] = a1r;  Mi[row * 33 + c1] = a1i;
            __syncthreads();
        }
        // Rot gates of layer l, reverse order q=4..0.
        // Right-mult by gate on qubit q: col_i <- u00*col_i + u10*col_j,
        //                                col_j <- u01*col_i + u11*col_j.
#pragma clang loop unroll(disable)
        for (int q = NQ - 1; q >= 0; --q) {
            const float* m = &gm[(l * NQ + q) * 8];
            const float u00r = m[0], u00i = m[1], u01r = m[2], u01i = m[3];
            const float u10r = m[4], u10i = m[5], u11r = m[6], u11i = m[7];
            const int sb = 16 >> q;
            const int lowm = sb - 1;
            const int i = ((p & ~lowm) << 1) | (p & lowm);
            const int j = i | sb;
            const int ii = row * 33 + i, jj = row * 33 + j;
            const float ar = Mr[ii], ai = Mi[ii];
            const float br = Mr[jj], bi = Mi[jj];
            Mr[ii] = u00r * ar - u00i * ai + u10r * br - u10i * bi;
            Mi[ii] = u00r * ai + u00i * ar + u10r * bi + u10i * br;
            Mr[jj] = u01r * ar - u01i * ai + u11r * br - u11i * bi;
            Mi[jj] = u01r * ai + u01i * ar + u11r * bi + u11i * br;
            __syncthreads();
        }
    }

    // ---- Emit f16 A-fragments: element (m,k) -> lane L=(k>>3)*16+m, reg k&7.
#pragma unroll
    for (int h = 0; h < 2; ++h) {
        const int idx = h * 256 + t;          // 0..511
        const int k = idx >> 4, m = idx & 15;
        const int L = (k >> 3) * 16 + m;
        const int jj = k & 7;
        afr[L * 8 + jj] = (_Float16)Mr[m * 33 + k];
        afi[L * 8 + jj] = (_Float16)Mi[m * 33 + k];
    }
    __syncthreads();

    // ---- GEMM: wave wv handles batches b0 + wv*128 .. +127 (8 tiles of 16).
    const int lane = t & 63;
    const int wv   = t >> 6;
    const int quad = lane >> 4;
    const int n    = lane & 15;

    const half8 Ar = *(const half8*)&afr[lane * 8];
    const half8 Ai = *(const half8*)&afi[lane * 8];

#pragma unroll
    for (int t8 = 0; t8 < 8; ++t8) {
        const int bl = wv * 128 + t8 * 16 + n;
        const int b  = b0 + bl;
        const float* C = &scC[bl * 5];
        const float* S = &scS[bl * 5];

        // B-frag bit-map (verified r2): k=quad*8+j; quad&2->q0, quad&1->q1,
        // j&4->q2, j&2->q3, j&1->q4.
        const float f01 = ((quad & 2) ? S[0] : C[0]) * ((quad & 1) ? S[1] : C[1]);
        const float a0 = f01 * C[2], a1 = f01 * S[2];
        const float b00 = a0 * C[3], b01 = a0 * S[3];
        const float b10 = a1 * C[3], b11 = a1 * S[3];

        half8 Bf;
        Bf[0] = (_Float16)(b00 * C[4]);  Bf[1] = (_Float16)(b00 * S[4]);
        Bf[2] = (_Float16)(b01 * C[4]);  Bf[3] = (_Float16)(b01 * S[4]);
        Bf[4] = (_Float16)(b10 * C[4]);  Bf[5] = (_Float16)(b10 * S[4]);
        Bf[6] = (_Float16)(b11 * C[4]);  Bf[7] = (_Float16)(b11 * S[4]);

        f32x4 accR = {0.f, 0.f, 0.f, 0.f};
        f32x4 accI = {0.f, 0.f, 0.f, 0.f};
        accR = __builtin_amdgcn_mfma_f32_16x16x32_f16(Ar, Bf, accR, 0, 0, 0);
        accI = __builtin_amdgcn_mfma_f32_16x16x32_f16(Ai, Bf, accI, 0, 0, 0);

        // C/D: col = lane&15 (batch), row = quad*4 + reg (output k).
        const float p0 = accR[0] * accR[0] + accI[0] * accI[0];
        const float p1 = accR[1] * accR[1] + accI[1] * accI[1];
        const float p2 = accR[2] * accR[2] + accI[2] * accI[2];
        const float p3 = accR[3] * accR[3] + accI[3] * accI[3];

        float mx = fmaxf(fmaxf(p0, p1), fmaxf(p2, p3));
        mx = fmaxf(mx, __shfl_xor(mx, 16));
        mx = fmaxf(mx, __shfl_xor(mx, 32));
        const float inv = 1.0f / mx;

        const float4 o = make_float4(p0 * inv, p1 * inv, p2 * inv, p3 * inv);
        *(float4*)(out + (size_t)b * 64 + g * 16 + quad * 4) = o;
    }
}

extern "C" void kernel_launch(void* const* d_in, const int* in_sizes, int n_in,
                              void* d_out, int out_size, void* d_ws, size_t ws_size,
                              hipStream_t stream) {
    const float* x = (const float*)d_in[0];   // [B, 5]
    const float* w = (const float*)d_in[1];   // [4, 4, 5, 3]
    float* out = (float*)d_out;               // [B, 64]
    const int B = in_sizes[0] / NQ;           // 65536

    // 4 g x 128 batch-blocks of 512 batches; 512 blocks = 2 per CU.
    pqg_fused<<<(B / 512) * NGEN, 256, 0, stream>>>(x, w, out);
}